// Round 1
// baseline (7776.671 us; speedup 1.0000x reference)
//
#include <hip/hip_runtime.h>

#define HD 768
#define G4 3072
#define T1 256
#define NS2 64
#define NL 3

__device__ __forceinline__ float sigf(float x) { return 1.0f / (1.0f + expf(-x)); }

// ---------------------------------------------------------------------------
// Tiled f32 GEMM: C[m, jg] = sum_k A[m,k] * W[jg, k] (+ bias[jg])
// A: [M,K] row stride lda. W: rows jg with row stride ldw (arbitrary base off).
// Output address: chunk = jg / n_per_chunk;
//   C[chunk*chunk_stride + (size_t)m*n_per_chunk + jg % n_per_chunk]
// (plain layout: n_per_chunk = N, chunk_stride = 0)
// grid: (N/64, M/64), block 256. Requires M%64==0, N%64==0, K%16==0,
// 64 | n_per_chunk boundaries.
// ---------------------------------------------------------------------------
__global__ __launch_bounds__(256) void gemm_f32(
    const float* __restrict__ A, int lda,
    const float* __restrict__ W, int ldw,
    const float* __restrict__ bias,
    float* __restrict__ C,
    int K, int n_per_chunk, long long chunk_stride)
{
    __shared__ __align__(16) float As[16 * 64];
    __shared__ __align__(16) float Ws[16 * 64];
    const int tid = threadIdx.x;
    const int tx = tid & 15, ty = tid >> 4;
    const int n0 = blockIdx.x * 64, m0 = blockIdx.y * 64;
    const int lr = tid >> 2, lc = tid & 3;

    float acc[4][4] = {{0.f}};
    const float* Ap = A + (size_t)(m0 + lr) * lda + lc * 4;
    const float* Wp = W + (size_t)(n0 + lr) * ldw + lc * 4;

    for (int k0 = 0; k0 < K; k0 += 16) {
        float4 av = *(const float4*)(Ap + k0);
        float4 wv = *(const float4*)(Wp + k0);
        __syncthreads();
        As[(lc * 4 + 0) * 64 + lr] = av.x;
        As[(lc * 4 + 1) * 64 + lr] = av.y;
        As[(lc * 4 + 2) * 64 + lr] = av.z;
        As[(lc * 4 + 3) * 64 + lr] = av.w;
        Ws[(lc * 4 + 0) * 64 + lr] = wv.x;
        Ws[(lc * 4 + 1) * 64 + lr] = wv.y;
        Ws[(lc * 4 + 2) * 64 + lr] = wv.z;
        Ws[(lc * 4 + 3) * 64 + lr] = wv.w;
        __syncthreads();
#pragma unroll
        for (int k = 0; k < 16; ++k) {
            float4 a = *(const float4*)&As[k * 64 + ty * 4];
            float4 b = *(const float4*)&Ws[k * 64 + tx * 4];
            float aa[4] = {a.x, a.y, a.z, a.w};
            float bb[4] = {b.x, b.y, b.z, b.w};
#pragma unroll
            for (int i = 0; i < 4; ++i)
#pragma unroll
                for (int j = 0; j < 4; ++j) acc[i][j] += aa[i] * bb[j];
        }
    }

    const int jg = n0 + tx * 4;
    const int chunk = jg / n_per_chunk;
    const int jo = jg - chunk * n_per_chunk;
    float4 bv = make_float4(0.f, 0.f, 0.f, 0.f);
    if (bias) bv = *(const float4*)&bias[jg];
    float* Cb = C + (size_t)chunk * chunk_stride + jo;
#pragma unroll
    for (int i = 0; i < 4; ++i) {
        const int m = m0 + ty * 4 + i;
        float4 o;
        o.x = acc[i][0] + bv.x;
        o.y = acc[i][1] + bv.y;
        o.z = acc[i][2] + bv.z;
        o.w = acc[i][3] + bv.w;
        *(float4*)&Cb[(size_t)m * n_per_chunk] = o;
    }
}

// ---------------------------------------------------------------------------
// One LSTM time step, both directions.
// Whh: [2][3072][768]. G(ih gates): [dir][b][t][3072]. h_cur/h_nxt/c: [2][4][768].
// Hout: [4][256][1536] (fwd units 0..767, bwd 768..1535). last -> tanh on Hout.
// grid (96, 2) (8 hidden units per block x 4 gates = 32 rows), block 256.
// ---------------------------------------------------------------------------
__global__ __launch_bounds__(256) void lstm_step(
    const float* __restrict__ Whh,
    const float* __restrict__ G,
    const float* __restrict__ h_cur,
    float* __restrict__ h_nxt,
    float* __restrict__ c_st,
    float* __restrict__ Hout,
    int s, int last)
{
    __shared__ __align__(16) float hs[4 * HD];  // [k][b]
    __shared__ float gl[32 * 4];                // [j_local][b]
    const int tid = threadIdx.x;
    const int dir = blockIdx.y;
    const int t = dir ? (T1 - 1 - s) : s;
    const int u0 = blockIdx.x * 8;

    const float* hsrc = h_cur + (size_t)dir * 4 * HD;  // [b][k]
    for (int idx = tid; idx < 4 * HD; idx += 256) {
        const int b = idx & 3, k = idx >> 2;
        hs[idx] = hsrc[b * HD + k];
    }
    __syncthreads();

    const int ks = tid & 7, jl = tid >> 3;      // 8 k-slices, 32 j rows
    const int g = jl >> 3, ui = jl & 7;
    const int j = g * HD + u0 + ui;

    const float4* wp = (const float4*)(Whh + ((size_t)dir * G4 + j) * HD);
    const float4* hs4 = (const float4*)hs;

    float a0 = 0.f, a1 = 0.f, a2 = 0.f, a3 = 0.f;
#pragma unroll 4
    for (int it = 0; it < 24; ++it) {
        const int kq = it * 8 + ks;             // float4 index; k = kq*4..kq*4+3
        float4 w = wp[kq];
        float4 hA = hs4[kq * 4 + 0];
        float4 hB = hs4[kq * 4 + 1];
        float4 hC = hs4[kq * 4 + 2];
        float4 hD = hs4[kq * 4 + 3];
        a0 += w.x * hA.x + w.y * hB.x + w.z * hC.x + w.w * hD.x;
        a1 += w.x * hA.y + w.y * hB.y + w.z * hC.y + w.w * hD.y;
        a2 += w.x * hA.z + w.y * hB.z + w.z * hC.z + w.w * hD.z;
        a3 += w.x * hA.w + w.y * hB.w + w.z * hC.w + w.w * hD.w;
    }
#pragma unroll
    for (int off = 1; off < 8; off <<= 1) {
        a0 += __shfl_xor(a0, off);
        a1 += __shfl_xor(a1, off);
        a2 += __shfl_xor(a2, off);
        a3 += __shfl_xor(a3, off);
    }
    if (ks == 0) {
        const size_t bstr = (size_t)T1 * G4;
        const size_t gb = (((size_t)dir * 4) * T1 + t) * G4 + j;
        gl[jl * 4 + 0] = a0 + G[gb];
        gl[jl * 4 + 1] = a1 + G[gb + bstr];
        gl[jl * 4 + 2] = a2 + G[gb + 2 * bstr];
        gl[jl * 4 + 3] = a3 + G[gb + 3 * bstr];
    }
    __syncthreads();

    if (tid < 32) {
        const int ui2 = tid >> 2, b = tid & 3;
        const float gi = gl[(0 * 8 + ui2) * 4 + b];
        const float gf = gl[(1 * 8 + ui2) * 4 + b];
        const float gg = gl[(2 * 8 + ui2) * 4 + b];
        const float go = gl[(3 * 8 + ui2) * 4 + b];
        const int u = u0 + ui2;
        const size_t ci = (size_t)dir * 4 * HD + b * HD + u;
        const float c = sigf(gf) * c_st[ci] + sigf(gi) * tanhf(gg);
        const float h = sigf(go) * tanhf(c);
        c_st[ci] = c;
        h_nxt[ci] = h;
        Hout[((size_t)b * T1 + t) * (2 * HD) + dir * HD + u] = last ? tanhf(h) : h;
    }
}

// ---------------------------------------------------------------------------
// Attention: per (b,q) block. hq includes attn_b1. hk: [4*256][768].
// A = mask ? exp(score + b2) : 0 ; Asum clipped at 2e-15 ; sf = (A/Asum) @ out.
// grid 256, block 256.
// ---------------------------------------------------------------------------
__global__ __launch_bounds__(256) void attn_kernel(
    const float* __restrict__ hq,
    const float* __restrict__ hk,
    const float* __restrict__ w2p,
    const float* __restrict__ b2p,
    const float* __restrict__ am,
    const float* __restrict__ sm,
    const float* __restrict__ H3,
    float* __restrict__ sf)
{
    __shared__ float hql[HD];
    __shared__ float w2[HD];
    __shared__ float Ash[T1];
    __shared__ float red[1];
    const int tid = threadIdx.x;
    const int bq = blockIdx.x;
    const int b = bq >> 6;

    for (int e = tid; e < HD; e += 256) {
        hql[e] = hq[(size_t)bq * HD + e];
        w2[e] = w2p[e];
    }
    __syncthreads();

    const int lane = tid & 63, wid = tid >> 6;
    const float amv = am[bq];
    const float b2 = b2p[0];
    for (int k = wid; k < T1; k += 4) {
        const float* hkp = hk + ((size_t)b * T1 + k) * HD;
        float s = 0.f;
#pragma unroll
        for (int i = 0; i < 12; ++i) {
            const int e = i * 64 + lane;
            float v = hql[e] + hkp[e];
            v = v > 0.f ? v : 0.f;
            s += v * w2[e];
        }
#pragma unroll
        for (int off = 32; off; off >>= 1) s += __shfl_xor(s, off);
        if (lane == 0) {
            const float m = amv * sm[b * T1 + k];
            Ash[k] = (m == 0.f) ? 0.f : expf(s + b2);
        }
    }
    __syncthreads();

    if (tid < 64) {
        float p = Ash[tid] + Ash[tid + 64] + Ash[tid + 128] + Ash[tid + 192];
#pragma unroll
        for (int off = 32; off; off >>= 1) p += __shfl_xor(p, off);
        if (tid == 0) red[0] = fmaxf(p, 2e-15f);
    }
    __syncthreads();
    const float inv = 1.f / red[0];

    for (int d = tid; d < 2 * HD; d += 256) {
        const float* hp = H3 + (size_t)b * T1 * 2 * HD + d;
        float acc = 0.f;
        for (int k = 0; k < T1; ++k) acc += Ash[k] * hp[(size_t)k * 2 * HD];
        sf[(size_t)bq * 2 * HD + d] = acc * inv;
    }
}

// state_semantic + val. grid 4, block 256.
__global__ __launch_bounds__(256) void val_kernel(
    const float* __restrict__ sf, const float* __restrict__ am,
    const float* __restrict__ vw, const float* __restrict__ vb,
    float* __restrict__ val)
{
    __shared__ float red[4];
    const int b = blockIdx.x, tid = threadIdx.x;
    float num = 0.f;
    for (int q = 0; q < NS2; ++q) num += am[b * NS2 + q];
    float acc = 0.f;
    for (int d = tid; d < 2 * HD; d += 256) {
        float s = 0.f;
        for (int q = 0; q < NS2; ++q) s += sf[((size_t)(b * NS2 + q)) * 2 * HD + d];
        acc += (s / num) * vw[d];
    }
#pragma unroll
    for (int off = 32; off; off >>= 1) acc += __shfl_xor(acc, off);
    if ((tid & 63) == 0) red[tid >> 6] = acc;
    __syncthreads();
    if (tid == 0) val[b] = red[0] + red[1] + red[2] + red[3] + vb[0];
}

// adv dot + mean-subtract + output. grid 4, block 256.
__global__ __launch_bounds__(256) void final_kernel(
    const float* __restrict__ Tb,   // [3][256][768]
    const float* __restrict__ act,  // [4][64][768]
    const float* __restrict__ bias, // [3]
    const float* __restrict__ val,  // [4]
    float* __restrict__ out)        // [256][3]
{
    __shared__ float adv[192];
    __shared__ float red[4];
    const int b = blockIdx.x, tid = threadIdx.x;
    const int lane = tid & 63, wid = tid >> 6;

    for (int idx = wid; idx < 192; idx += 4) {
        const int q = idx / 3, l = idx - q * 3;
        const float* tp = Tb + (size_t)l * T1 * HD + (size_t)(b * NS2 + q) * HD;
        const float* ap = act + (size_t)(b * NS2 + q) * HD;
        float s = 0.f;
#pragma unroll
        for (int i = 0; i < 12; ++i) {
            const int h = i * 64 + lane;
            s += tp[h] * ap[h];
        }
#pragma unroll
        for (int off = 32; off; off >>= 1) s += __shfl_xor(s, off);
        if (lane == 0) adv[idx] = s + bias[l];
    }
    __syncthreads();
    float part = (tid < 192) ? adv[tid] : 0.f;
#pragma unroll
    for (int off = 32; off; off >>= 1) part += __shfl_xor(part, off);
    if (lane == 0) red[wid] = part;
    __syncthreads();
    const float mean = (red[0] + red[1] + red[2] + red[3]) * (1.f / 192.f);
    const float vv = val[b];
    for (int idx = tid; idx < 192; idx += 256) {
        const int q = idx / 3, l = idx - q * 3;
        out[(size_t)(b * NS2 + q) * NL + l] = vv + adv[idx] - mean;
    }
}

// ---------------------------------------------------------------------------
extern "C" void kernel_launch(void* const* d_in, const int* in_sizes, int n_in,
                              void* d_out, int out_size, void* d_ws, size_t ws_size,
                              hipStream_t stream)
{
    const float* states = (const float*)d_in[0];
    const float* state_mask = (const float*)d_in[1];
    const float* actions = (const float*)d_in[2];
    const float* actions_mask = (const float*)d_in[3];
    const float* Wih0 = (const float*)d_in[4];   // [2,3072,768]
    const float* Whh0 = (const float*)d_in[5];   // [2,3072,768]
    const float* b0 = (const float*)d_in[6];     // [2,3072]
    const float* Wih12 = (const float*)d_in[7];  // [2,2,3072,1536]
    const float* Whh12 = (const float*)d_in[8];  // [2,2,3072,768]
    const float* b12 = (const float*)d_in[9];    // [2,2,3072]
    const float* aW1 = (const float*)d_in[10];   // [768,2304]
    const float* ab1 = (const float*)d_in[11];   // [768]
    const float* aW2 = (const float*)d_in[12];   // [1,768]
    const float* ab2 = (const float*)d_in[13];   // [1]
    const float* vW = (const float*)d_in[14];    // [1,1536]
    const float* vb = (const float*)d_in[15];    // [1]
    const float* wgt = (const float*)d_in[16];   // [3,768,1536]
    const float* bias = (const float*)d_in[17];  // [3]
    float* out = (float*)d_out;

    float* ws = (float*)d_ws;
    float* G = ws;                        // [2][4][256][3072] = 6291456 floats
    float* B1 = G + 6291456;              // H1, later H3  (1572864)
    float* B2 = B1 + 1572864;             // H2            (1572864)
    float* hc = B2 + 1572864;             // h ping-pong (2*6144) + c (6144)
    float* h_st = hc;
    float* c_st = hc + 12288;
    // after LSTM phase, G region is reused for attention temporaries:
    float* hq = G;                        // 256*768   = 196608
    float* hkb = G + 196608;              // 1024*768  = 786432
    float* sf = G + 983040;               // 256*1536  = 393216
    float* Tb = G + 1376256;              // 3*256*768 = 589824
    float* val = G + 1966080;             // 4

    const dim3 blk(256);
    const long long gstride = (long long)4 * T1 * G4;  // per-direction chunk in G

    // ---------------- layer 0 ----------------
    hipMemsetAsync(hc, 0, (size_t)18432 * sizeof(float), stream);
    gemm_f32<<<dim3(6144 / 64, 1024 / 64), blk, 0, stream>>>(
        states, HD, Wih0, HD, b0, G, HD, G4, gstride);
    for (int s = 0; s < T1; ++s) {
        const float* hcur = h_st + (s & 1) * 6144;
        float* hnxt = h_st + ((s + 1) & 1) * 6144;
        lstm_step<<<dim3(96, 2), blk, 0, stream>>>(Whh0, G, hcur, hnxt, c_st, B1, s, 0);
    }
    // ---------------- layer 1 ----------------
    hipMemsetAsync(hc, 0, (size_t)18432 * sizeof(float), stream);
    gemm_f32<<<dim3(6144 / 64, 1024 / 64), blk, 0, stream>>>(
        B1, 2 * HD, Wih12, 2 * HD, b12, G, 2 * HD, G4, gstride);
    for (int s = 0; s < T1; ++s) {
        const float* hcur = h_st + (s & 1) * 6144;
        float* hnxt = h_st + ((s + 1) & 1) * 6144;
        lstm_step<<<dim3(96, 2), blk, 0, stream>>>(Whh12, G, hcur, hnxt, c_st, B2, s, 0);
    }
    // ---------------- layer 2 ----------------
    hipMemsetAsync(hc, 0, (size_t)18432 * sizeof(float), stream);
    gemm_f32<<<dim3(6144 / 64, 1024 / 64), blk, 0, stream>>>(
        B2, 2 * HD, Wih12 + (size_t)6144 * 1536, 2 * HD, b12 + 6144, G, 2 * HD, G4, gstride);
    const float* Whh2 = Whh12 + (size_t)2 * G4 * HD;
    for (int s = 0; s < T1; ++s) {
        const float* hcur = h_st + (s & 1) * 6144;
        float* hnxt = h_st + ((s + 1) & 1) * 6144;
        lstm_step<<<dim3(96, 2), blk, 0, stream>>>(Whh2, G, hcur, hnxt, c_st, B1, s, 1);
    }
    // ---------------- attention ----------------
    // hq = actions @ W1q^T + b1   (W1q = aW1[:, :768], row stride 2304)
    gemm_f32<<<dim3(768 / 64, 256 / 64), blk, 0, stream>>>(
        actions, HD, aW1, 2304, ab1, hq, HD, HD, 0);
    // hk = out @ W1k^T            (W1k = aW1[:, 768:2304], K = 1536)
    gemm_f32<<<dim3(768 / 64, 1024 / 64), blk, 0, stream>>>(
        B1, 2 * HD, aW1 + 768, 2304, nullptr, hkb, 2 * HD, HD, 0);
    attn_kernel<<<dim3(256), blk, 0, stream>>>(hq, hkb, aW2, ab2, actions_mask,
                                               state_mask, B1, sf);
    val_kernel<<<dim3(4), blk, 0, stream>>>(sf, actions_mask, vW, vb, val);
    // T_l = sf @ weight[l]^T
    for (int l = 0; l < NL; ++l) {
        gemm_f32<<<dim3(768 / 64, 256 / 64), blk, 0, stream>>>(
            sf, 2 * HD, wgt + (size_t)l * HD * 2 * HD, 2 * HD, nullptr,
            Tb + (size_t)l * T1 * HD, 2 * HD, HD, 0);
    }
    final_kernel<<<dim3(4), blk, 0, stream>>>(Tb, actions, bias, val, out);
}